// Round 1
// baseline (368.796 us; speedup 1.0000x reference)
//
#include <hip/hip_runtime.h>
#include <math.h>

// Problem: N=100000 nodes, D=512, E=6400000 edges.
// gate[n] = sigmoid(dot(x[n,:], p) + b)
// out[0:2E)   = float(edge_index)            (tuple output 0, exact in f32)
// out[2E:3E)  = edge_attr[e] * gate[col[e]]  (col = edge_index[E + e])

// ---------------- Kernel 1: per-row matvec + sigmoid -----------------
// One wave (64 lanes) per row. D=512 = 64 lanes * 8 floats -> each lane
// reads two float4 (32 B contiguous per lane, wave covers the full 2 KB row
// coalesced). p (2 KB) stays L1-resident across rows.
__global__ __launch_bounds__(256) void gate_kernel(
    const float* __restrict__ x,
    const float* __restrict__ p,
    const float* __restrict__ b,
    float* __restrict__ gate,
    int N)
{
    const int wave_id = (blockIdx.x * blockDim.x + threadIdx.x) >> 6;
    const int lane    = threadIdx.x & 63;
    const int nwaves  = (gridDim.x * blockDim.x) >> 6;
    const float bb = b[0];

    const float4* pr = (const float4*)p;
    float4 p0 = pr[lane * 2];
    float4 p1 = pr[lane * 2 + 1];

    for (int row = wave_id; row < N; row += nwaves) {
        const float4* xr = (const float4*)(x + (size_t)row * 512);
        float4 x0 = xr[lane * 2];
        float4 x1 = xr[lane * 2 + 1];
        float s = x0.x * p0.x + x0.y * p0.y + x0.z * p0.z + x0.w * p0.w
                + x1.x * p1.x + x1.y * p1.y + x1.z * p1.z + x1.w * p1.w;
        // wave64 shuffle reduction
        #pragma unroll
        for (int off = 32; off > 0; off >>= 1)
            s += __shfl_down(s, off, 64);
        if (lane == 0) {
            float t = s + bb;
            gate[row] = 1.0f / (1.0f + __expf(-t));
        }
    }
}

// ---------------- Kernel 2: index copy + edge gather/scale -----------------
__global__ __launch_bounds__(256) void edge_kernel(
    const int*   __restrict__ edge_index,  // [2*E] int32
    const float* __restrict__ edge_attr,   // [E]
    const float* __restrict__ gate,        // [N] (L2-resident, 400 KB)
    float* __restrict__ out,               // [3*E] f32
    int E)
{
    const int tid    = blockIdx.x * blockDim.x + threadIdx.x;
    const int stride = gridDim.x * blockDim.x;

    const int EI4 = (2 * E) >> 2;   // quads of edge_index
    const int EV4 = E >> 2;         // quads of values

    // 1) copy edge_index -> float(out[0:2E)), vectorized int4 -> float4
    const int4*  ei4  = (const int4*)edge_index;
    float4*      out4 = (float4*)out;
    for (int i = tid; i < EI4; i += stride) {
        int4 v = ei4[i];
        out4[i] = make_float4((float)v.x, (float)v.y, (float)v.z, (float)v.w);
    }

    // 2) out[2E + e] = edge_attr[e] * gate[edge_index[E + e]]
    const int4*   col4 = (const int4*)(edge_index + E);
    const float4* ea4  = (const float4*)edge_attr;
    float4*       ov4  = (float4*)(out + 2 * (size_t)E);
    for (int i = tid; i < EV4; i += stride) {
        int4   c = col4[i];
        float4 a = ea4[i];
        float4 r;
        r.x = a.x * gate[c.x];
        r.y = a.y * gate[c.y];
        r.z = a.z * gate[c.z];
        r.w = a.w * gate[c.w];
        ov4[i] = r;
    }
}

extern "C" void kernel_launch(void* const* d_in, const int* in_sizes, int n_in,
                              void* d_out, int out_size, void* d_ws, size_t ws_size,
                              hipStream_t stream) {
    const float* x          = (const float*)d_in[0];   // [N, 512]
    const int*   edge_index = (const int*)  d_in[1];   // [2, E] (int32 on device)
    const float* edge_attr  = (const float*)d_in[2];   // [E]
    const float* p          = (const float*)d_in[3];   // [512, 1]
    const float* b          = (const float*)d_in[4];   // [1]

    const int D = in_sizes[3];            // 512
    const int N = in_sizes[0] / D;        // 100000
    const int E = in_sizes[2];            // 6400000

    float* gate = (float*)d_ws;           // N floats = 400 KB scratch
    float* out  = (float*)d_out;

    // Kernel 1: one wave per row -> N waves -> N/4 blocks of 256
    int gate_blocks = (N + 3) / 4;        // 4 waves per 256-thread block
    gate_kernel<<<gate_blocks, 256, 0, stream>>>(x, p, b, gate, N);

    // Kernel 2: cover the larger loop (2E/4 quads) with one pass
    int edge_blocks = ((2 * E / 4) + 255) / 256;   // 12500 blocks
    edge_kernel<<<edge_blocks, 256, 0, stream>>>(edge_index, edge_attr, gate, out, E);
}